// Round 5
// baseline (178.596 us; speedup 1.0000x reference)
//
#include <hip/hip_runtime.h>
#include <cstdint>

#define NB 8
#define TS 2048
#define NE 1024
#define HD 64
#define MTOT (NB*TS)

typedef float     f4  __attribute__((ext_vector_type(4)));
typedef short     s8v __attribute__((ext_vector_type(8)));
typedef short     s4v __attribute__((ext_vector_type(4)));
typedef int       i4v __attribute__((ext_vector_type(4)));
typedef _Float16  h8  __attribute__((ext_vector_type(8)));

__device__ __forceinline__ short f2bf(float f) {  // RNE
  union { float f; uint32_t u; } x; x.f = f;
  return (short)((x.u + 0x7FFFu + ((x.u >> 16) & 1u)) >> 16);
}

// pack two fp32 -> (bf16(lo) | bf16(hi)<<16) via +0x8000 round + v_perm byte select
__device__ __forceinline__ int pack2(float lo, float hi) {
  union { float f; uint32_t u; } a, b; a.f = lo; b.f = hi;
  return (int)__builtin_amdgcn_perm(b.u + 0x8000u, a.u + 0x8000u, 0x07060302u);
}

// ---- kernel 0: W fp32 -> bf16 (q-scale folded). wb [192][1024]: rows 0-63 q, 64-127 k, 128-191 v
__global__ __launch_bounds__(256) void wconv_kernel(
    const float* __restrict__ Wk, const float* __restrict__ Wq, const float* __restrict__ Wv,
    short* __restrict__ wb)
{
  const int idx = (blockIdx.x * 256 + threadIdx.x) * 4;
  const int p = idx >> 16;
  const int off = idx & 65535;
  const float* W = (p == 0) ? Wq : (p == 1) ? Wk : Wv;
  const float s = (p == 0) ? 0.18033688011112042f : 1.0f; // (1/8)*log2(e)
  const float4 v = *(const float4*)&W[off];
  s4v h; h[0] = f2bf(v.x*s); h[1] = f2bf(v.y*s); h[2] = f2bf(v.z*s); h[3] = f2bf(v.w*s);
  *(s4v*)&wb[idx] = h;
}

// ---- kernel 1: FUSED projection (q,k,v in one pass over x). grid 512 x 256 thr.
// Block = 32 rows x 192 cols; wave = 32 rows x 48 cols (2 m-tiles x 3 n-frags).
// x staged once in LDS (dbuf, stride 72 = 16B aligned), W frags from L2 per-wave (no dup).
__global__ __launch_bounds__(256, 2) void proj_kernel(
    const float* __restrict__ x, const short* __restrict__ wb,
    short* __restrict__ qo, short* __restrict__ ko, _Float16* __restrict__ vo)
{
  __shared__ short xs[2][32][72];
  const int tid = threadIdx.x;
  const int wv = tid >> 6, lane = tid & 63, n = lane & 15, quad = lane >> 4;
  const int r0 = blockIdx.x * 32;
  const int srow = tid >> 3, sc8 = (tid & 7) * 8;     // stage: row 0..31, 8 fp32 cols per thread
  const float* xb = x + (size_t)(r0 + srow) * NE + sc8;
  const short* wcol = wb + (size_t)(wv * 48 + n) * NE + quad * 8;

  const f4 fz = {0.f, 0.f, 0.f, 0.f};
  f4 acc[2][3];
#pragma unroll
  for (int m = 0; m < 2; ++m)
#pragma unroll
    for (int nf = 0; nf < 3; ++nf) acc[m][nf] = fz;

  auto loadX = [&](int t, float4* d) {
    d[0] = *(const float4*)&xb[t * 64];
    d[1] = *(const float4*)&xb[t * 64 + 4];
  };
  auto writeX = [&](int buf, const float4* d) {
    i4v w;
    w[0] = pack2(d[0].x, d[0].y); w[1] = pack2(d[0].z, d[0].w);
    w[2] = pack2(d[1].x, d[1].y); w[3] = pack2(d[1].z, d[1].w);
    *(i4v*)&xs[buf][srow][sc8] = w;
  };
  auto loadB = [&](int t, s8v (*b)[2]) {
#pragma unroll
    for (int nf = 0; nf < 3; ++nf)
#pragma unroll
      for (int kc = 0; kc < 2; ++kc)
        b[nf][kc] = *(const s8v*)&wcol[(size_t)nf * 16 * NE + t * 64 + kc * 32];
  };

  float4 x1[2], x2[2];
  s8v b0[3][2], b1[3][2];
  {
    float4 x0[2];
    loadX(0, x0); loadX(1, x1); loadX(2, x2);
    loadB(0, b0); loadB(1, b1);
    writeX(0, x0);
  }
  __syncthreads();

#pragma unroll
  for (int t = 0; t < 16; ++t) {
    float4 xn[2]; s8v bn[3][2];
    if (t + 3 < 16) loadX(t + 3, xn);
    if (t + 2 < 16) loadB(t + 2, bn);

    s8v a[2][2];
#pragma unroll
    for (int m = 0; m < 2; ++m)
#pragma unroll
      for (int kc = 0; kc < 2; ++kc)
        a[m][kc] = *(const s8v*)&xs[t & 1][m * 16 + n][kc * 32 + quad * 8];

#pragma unroll
    for (int m = 0; m < 2; ++m)
#pragma unroll
      for (int nf = 0; nf < 3; ++nf) {
        acc[m][nf] = __builtin_amdgcn_mfma_f32_16x16x32_bf16(a[m][0], b0[nf][0], acc[m][nf], 0, 0, 0);
        acc[m][nf] = __builtin_amdgcn_mfma_f32_16x16x32_bf16(a[m][1], b0[nf][1], acc[m][nf], 0, 0, 0);
      }

    if (t + 1 < 16) writeX((t + 1) & 1, x1);
#pragma unroll
    for (int u = 0; u < 2; ++u) { x1[u] = x2[u]; x2[u] = xn[u]; }
#pragma unroll
    for (int nf = 0; nf < 3; ++nf)
#pragma unroll
      for (int kc = 0; kc < 2; ++kc) { b0[nf][kc] = b1[nf][kc]; b1[nf][kc] = bn[nf][kc]; }
    __syncthreads();
  }

  // epilogue: C row = quad*4+i (+16m), col lane-index n -> global col gc
#pragma unroll
  for (int m = 0; m < 2; ++m)
#pragma unroll
    for (int nf = 0; nf < 3; ++nf) {
      const int gc = wv * 48 + nf * 16 + n;   // 0..191
      const int p = gc >> 6, r = gc & 63;     // p uniform per (wv,nf)
#pragma unroll
      for (int i = 0; i < 4; ++i) {
        const int R = r0 + m * 16 + quad * 4 + i;
        const float av = acc[m][nf][i];
        if (p == 0)      qo[(size_t)R * HD + r] = f2bf(av);
        else if (p == 1) ko[(size_t)R * HD + r] = f2bf(av);
        else {
          // V transposed [b][d][t'] with key order swizzled so attn PV B-frags are single 16B loads
          const int t2 = R & (TS - 1), b = t2 & 31;
          const int pos = (t2 & ~31) | (((b >> 2) & 3) << 3) | (((b >> 4) & 1) << 2) | (b & 3);
          vo[(size_t)(R >> 11) * HD * TS + (size_t)r * TS + pos] = (_Float16)av;
        }
      }
    }
}

// ---- kernel 2: attention. grid 1024 x 256 thr (4 waves). 16 q/block, 4-way key split
// (512 keys/wave). Low VGPR (launch_bounds(256,3)) -> 12 waves/CU for latency hiding.
__global__ __launch_bounds__(256, 3) void attn_kernel(
    const short* __restrict__ q, const short* __restrict__ k,
    const _Float16* __restrict__ vT, float* __restrict__ out)
{
  __shared__ float o_c[4][16][68];
  __shared__ float l_c[4][16];

  const int tid = threadIdx.x;
  const int wv = tid >> 6, lane = tid & 63, n = lane & 15, quad = lane >> 4;
  const int batch = blockIdx.x & 7;          // XCD swizzle: batch's K/V pinned per XCD L2
  const int qg = blockIdx.x >> 3;
  const int m0 = batch * TS + qg * 16;
  const short*    kb = k  + (size_t)batch * TS * HD;
  const _Float16* vb = vT + (size_t)batch * HD * TS;
  const f4 fz = {0.f, 0.f, 0.f, 0.f};

  s8v qf[2];
#pragma unroll
  for (int kc = 0; kc < 2; ++kc)
    qf[kc] = *(const s8v*)&q[(size_t)(m0 + n) * HD + kc * 32 + quad * 8];

  f4 o[4] = {fz, fz, fz, fz};
  f4 lD = fz;
  h8 ones;
#pragma unroll
  for (int j = 0; j < 8; ++j) ones[j] = (_Float16)1.0f;

#pragma unroll 2
  for (int it = 0; it < 8; ++it) {
    const int c0 = wv * 512 + it * 64;

    // all loads issued at iter top (K row-major, V swizzled-transposed single 16B)
    s8v kf[4][2];
#pragma unroll
    for (int f = 0; f < 4; ++f)
#pragma unroll
      for (int kc = 0; kc < 2; ++kc)
        kf[f][kc] = *(const s8v*)&kb[(size_t)(c0 + f * 16 + n) * HD + kc * 32 + quad * 8];
    h8 vf[2][4];
#pragma unroll
    for (int pr = 0; pr < 2; ++pr)
#pragma unroll
      for (int g = 0; g < 4; ++g)
        vf[pr][g] = *(const h8*)&vb[(size_t)(g * 16 + n) * TS + c0 + pr * 32 + quad * 8];

    // S^T = K Q^T: row=key(quad*4+i of tile f), col=q(n)
    f4 st[4];
#pragma unroll
    for (int f = 0; f < 4; ++f) {
      st[f] = __builtin_amdgcn_mfma_f32_16x16x32_bf16(kf[f][0], qf[0], fz, 0, 0, 0);
      st[f] = __builtin_amdgcn_mfma_f32_16x16x32_bf16(kf[f][1], qf[1], st[f], 0, 0, 0);
    }

    // P = exp2(S) in-register -> f16 A-frags (tile pair pr; hf selects j<4 / j>=4)
    h8 pa[2];
#pragma unroll
    for (int pr = 0; pr < 2; ++pr)
#pragma unroll
      for (int hf = 0; hf < 2; ++hf)
#pragma unroll
        for (int i = 0; i < 4; ++i)
          pa[pr][hf * 4 + i] = (_Float16)__builtin_amdgcn_exp2f(st[pr * 2 + hf][i]);

    // O += P V ; l += P * 1 (row-sums via MFMA, key-reduced in-accumulator)
#pragma unroll
    for (int pr = 0; pr < 2; ++pr) {
      lD = __builtin_amdgcn_mfma_f32_16x16x32_f16(pa[pr], ones, lD, 0, 0, 0);
#pragma unroll
      for (int g = 0; g < 4; ++g)
        o[g] = __builtin_amdgcn_mfma_f32_16x16x32_f16(pa[pr], vf[pr][g], o[g], 0, 0, 0);
    }
  }

  if (n == 0)
#pragma unroll
    for (int i = 0; i < 4; ++i) l_c[wv][quad * 4 + i] = lD[i];
#pragma unroll
  for (int g = 0; g < 4; ++g)
#pragma unroll
    for (int i = 0; i < 4; ++i)
      o_c[wv][quad * 4 + i][g * 16 + n] = o[g][i];
  __syncthreads();

  // combine 4 key-splits: 256 thr = 16 q x 16 d4-groups
  const int qr = tid >> 4, d4 = (tid & 15) * 4;
  const float L = l_c[0][qr] + l_c[1][qr] + l_c[2][qr] + l_c[3][qr];
  const float inv = 1.0f / L;
  f4 s = fz;
#pragma unroll
  for (int w = 0; w < 4; ++w) s += *(const f4*)&o_c[w][qr][d4];
  s *= inv;
  *(f4*)&out[(size_t)(m0 + qr) * HD + d4] = s;
}

extern "C" void kernel_launch(void* const* d_in, const int* in_sizes, int n_in,
                              void* d_out, int out_size, void* d_ws, size_t ws_size,
                              hipStream_t stream) {
  const float* x  = (const float*)d_in[0];
  const float* Wk = (const float*)d_in[1];
  const float* Wq = (const float*)d_in[2];
  const float* Wv = (const float*)d_in[3];
  float* out = (float*)d_out;

  short* qb = (short*)d_ws;                           // [MTOT][64] bf16 (pre-scaled)
  short* kb = qb + (size_t)MTOT * HD;                 // [MTOT][64] bf16
  _Float16* vb = (_Float16*)(kb + (size_t)MTOT * HD); // [NB][64][TS] f16, key-swizzled
  short* wb = (short*)(vb + (size_t)NB * HD * TS);    // [192][1024] bf16 weights

  wconv_kernel<<<192, 256, 0, stream>>>(Wk, Wq, Wv, wb);
  proj_kernel<<<MTOT / 32, 256, 0, stream>>>(x, wb, qb, kb, vb);
  attn_kernel<<<1024, 256, 0, stream>>>(qb, kb, vb, out);
}

// Round 6
// 160.456 us; speedup vs baseline: 1.1131x; 1.1131x over previous
//
#include <hip/hip_runtime.h>
#include <cstdint>

#define NB 8
#define TS 2048
#define NE 1024
#define HD 64
#define MTOT (NB*TS)

typedef float     f4  __attribute__((ext_vector_type(4)));
typedef short     s8v __attribute__((ext_vector_type(8)));
typedef short     s4v __attribute__((ext_vector_type(4)));
typedef int       i4v __attribute__((ext_vector_type(4)));
typedef _Float16  h8  __attribute__((ext_vector_type(8)));

__device__ __forceinline__ short f2bf(float f) {  // RNE
  union { float f; uint32_t u; } x; x.f = f;
  return (short)((x.u + 0x7FFFu + ((x.u >> 16) & 1u)) >> 16);
}

// pack two fp32 -> (bf16(lo) | bf16(hi)<<16) via +0x8000 round + v_perm byte select
__device__ __forceinline__ int pack2(float lo, float hi) {
  union { float f; uint32_t u; } a, b; a.f = lo; b.f = hi;
  return (int)__builtin_amdgcn_perm(b.u + 0x8000u, a.u + 0x8000u, 0x07060302u);
}

// async global->LDS DMA, 16B per lane. lptr must be wave-uniform; lane i lands at lptr+i*16.
__device__ __forceinline__ void gl2lds(const void* gptr, void* lptr) {
  auto g = (const __attribute__((address_space(1))) uint32_t*)gptr;
  auto l = (__attribute__((address_space(3))) uint32_t*)lptr;
  __builtin_amdgcn_global_load_lds(g, l, 16, 0, 0);
}

// AITER-style barrier: wait only until N vmem ops remain outstanding (keep prefetch flying)
template <int N>
__device__ __forceinline__ void wait_barrier() {
  asm volatile("s_waitcnt vmcnt(%0) lgkmcnt(0)" :: "n"(N) : "memory");
  __builtin_amdgcn_s_barrier();
}

// ---- kernel 0: W fp32 -> bf16 (q-scale folded). wb [192][1024]: 0-63 q, 64-127 k, 128-191 v
__global__ __launch_bounds__(256) void wconv_kernel(
    const float* __restrict__ Wk, const float* __restrict__ Wq, const float* __restrict__ Wv,
    short* __restrict__ wb)
{
  const int idx = (blockIdx.x * 256 + threadIdx.x) * 4;
  const int p = idx >> 16;
  const int off = idx & 65535;
  const float* W = (p == 0) ? Wq : (p == 1) ? Wk : Wv;
  const float s = (p == 0) ? 0.18033688011112042f : 1.0f; // (1/8)*log2(e)
  const float4 v = *(const float4*)&W[off];
  s4v h; h[0] = f2bf(v.x*s); h[1] = f2bf(v.y*s); h[2] = f2bf(v.z*s); h[3] = f2bf(v.w*s);
  *(s4v*)&wb[idx] = h;
}

// ---- kernel 1: fused qkv projection, global_load_lds pipeline. grid 256 x 256 thr.
// Tile 64 rows x 192 cols; wave = 32 rows x 96 cols. x: 4-buf fp32, 3-ahead; W: 3-buf bf16, 2-ahead.
// XOR slot-swizzle on LDS placement (DMA can't pad) -> 2-way banks = free.
__global__ __launch_bounds__(256) void proj_kernel(
    const float* __restrict__ x, const short* __restrict__ wb,
    short* __restrict__ qo, short* __restrict__ ko, _Float16* __restrict__ vo)
{
  __shared__ float Xs[4][64][64];    // 64 KB
  __shared__ short Ws[3][192][64];   // 72 KB
  const int tid = threadIdx.x;
  const int wv = tid >> 6, lane = tid & 63, n = lane & 15, quad = lane >> 4;
  const int mg = wv & 1, cg = wv >> 1;
  const int r0 = blockIdx.x * 64;
  const int xrow = lane >> 4, xslot = lane & 15;   // x DMA: 4 rows x 16 slots/instr
  const int wrow = lane >> 3, wslot = lane & 7;    // W DMA: 8 cols x 8 slots/instr

  auto dmaW = [&](int c, int buf) {
#pragma unroll
    for (int u = 0; u < 6; ++u) {
      const int C0 = (wv * 6 + u) * 8;
      const int col = C0 + wrow;
      const int gs = (wslot + col) & 7;            // lds[col][s] = global slot (s+col)&7
      gl2lds(&wb[(size_t)col * NE + c * 64 + gs * 8], &Ws[buf][C0][0]);
    }
  };
  auto dmaX = [&](int c, int buf) {
#pragma unroll
    for (int u = 0; u < 4; ++u) {
      const int R0 = (wv * 4 + u) * 4;
      const int row = R0 + xrow;
      const int gs = (xslot + row) & 15;           // lds[row][s] = global slot (s+row)&15
      gl2lds(&x[(size_t)(r0 + row) * NE + c * 64 + gs * 4], &Xs[buf][R0][0]);
    }
  };

  const f4 fz = {0.f, 0.f, 0.f, 0.f};
  f4 acc[2][6];
#pragma unroll
  for (int m = 0; m < 2; ++m)
#pragma unroll
    for (int nf = 0; nf < 6; ++nf) acc[m][nf] = fz;

  auto body = [&](int t, int bw, int bx, bool iw, bool ix) {
    if (iw) dmaW(t + 2, (t + 2) % 3);
    if (ix) dmaX(t + 3, (t + 3) & 3);
    // A frags: read swizzled fp32, convert to bf16 in-reg
    s8v a[2][2];
#pragma unroll
    for (int m = 0; m < 2; ++m)
#pragma unroll
      for (int kc = 0; kc < 2; ++kc) {
        const int row = mg * 32 + m * 16 + n;
        const int u0 = kc * 8 + quad * 2;
        const float* pr = &Xs[bx][row][0];
        const f4 f0 = *(const f4*)(pr + (((u0    ) - row) & 15) * 4);
        const f4 f1 = *(const f4*)(pr + (((u0 + 1) - row) & 15) * 4);
        i4v ai;
        ai[0] = pack2(f0[0], f0[1]); ai[1] = pack2(f0[2], f0[3]);
        ai[2] = pack2(f1[0], f1[1]); ai[3] = pack2(f1[2], f1[3]);
        a[m][kc] = __builtin_bit_cast(s8v, ai);
      }
    // B frags + MFMA
#pragma unroll
    for (int nf = 0; nf < 6; ++nf) {
      const int col = cg * 96 + nf * 16 + n;
      const s8v b0 = *(const s8v*)&Ws[bw][col][(((0 * 4 + quad) - col) & 7) * 8];
      const s8v b1 = *(const s8v*)&Ws[bw][col][(((1 * 4 + quad) - col) & 7) * 8];
      acc[0][nf] = __builtin_amdgcn_mfma_f32_16x16x32_bf16(a[0][0], b0, acc[0][nf], 0, 0, 0);
      acc[0][nf] = __builtin_amdgcn_mfma_f32_16x16x32_bf16(a[0][1], b1, acc[0][nf], 0, 0, 0);
      acc[1][nf] = __builtin_amdgcn_mfma_f32_16x16x32_bf16(a[1][0], b0, acc[1][nf], 0, 0, 0);
      acc[1][nf] = __builtin_amdgcn_mfma_f32_16x16x32_bf16(a[1][1], b1, acc[1][nf], 0, 0, 0);
    }
  };

  // prologue: [W0, x0, W1, x1, x2] -> after x0 there are 14 younger ops
  dmaW(0, 0); dmaX(0, 0); dmaW(1, 1); dmaX(1, 1); dmaX(2, 2);
  wait_barrier<14>();

  for (int t = 0; t <= 12; ++t) {               // issues W(t+2), x(t+3); drain keeps 14 newest
    body(t, t % 3, t & 3, true, true);
    wait_barrier<14>();
  }
  body(13, 1, 1, true, false);  wait_barrier<10>();   // W15 + x15 remain
  body(14, 2, 2, false, false); wait_barrier<0>();
  body(15, 0, 3, false, false);

  // epilogue
#pragma unroll
  for (int nf = 0; nf < 6; ++nf) {
    const int base = cg * 96 + nf * 16;
    const int p = base >> 6;
    const int rcol = (base & 63) + n;
#pragma unroll
    for (int m = 0; m < 2; ++m)
#pragma unroll
      for (int i = 0; i < 4; ++i) {
        const int R = r0 + mg * 32 + m * 16 + quad * 4 + i;
        const float av = acc[m][nf][i];
        if (p == 0)      qo[(size_t)R * HD + rcol] = f2bf(av);
        else if (p == 1) ko[(size_t)R * HD + rcol] = f2bf(av);
        else {
          // V transposed [b][d][t'] + key-order swizzle so attn PV B-frags are single 16B loads
          const int t2 = R & (TS - 1), b = t2 & 31;
          const int pos = (t2 & ~31) | (((b >> 2) & 3) << 3) | (((b >> 4) & 1) << 2) | (b & 3);
          vo[(size_t)(R >> 11) * HD * TS + (size_t)rcol * TS + pos] = (_Float16)av;
        }
      }
  }
}

// ---- kernel 2: attention, global_load_lds pipeline. grid 256 x 256 thr (4 waves).
// 64 q/block (wave owns 16 q over ALL 2048 keys -> no combine); K/V chunks of 64 keys,
// 3-buf 2-ahead DMA, vmcnt(4) barriers. l via P*ones MFMA.
__global__ __launch_bounds__(256) void attn_kernel(
    const short* __restrict__ q, const short* __restrict__ k,
    const _Float16* __restrict__ vT, float* __restrict__ out)
{
  __shared__ short    Ks[3][64][64];   // 24 KB
  __shared__ _Float16 Vs[3][64][64];   // 24 KB
  const int tid = threadIdx.x;
  const int wv = tid >> 6, lane = tid & 63, n = lane & 15, quad = lane >> 4;
  const int batch = blockIdx.x & 7;            // XCD swizzle: batch K/V pinned per XCD L2
  const int qg = blockIdx.x >> 3;
  const int m0 = batch * TS + qg * 64;
  const short*    kb = k  + (size_t)batch * TS * HD;
  const _Float16* vb = vT + (size_t)batch * HD * TS;
  const int drow = lane >> 3, dslot = lane & 7;
  const f4 fz = {0.f, 0.f, 0.f, 0.f};

  auto dmaKV = [&](int c, int buf) {
#pragma unroll
    for (int u = 0; u < 2; ++u) {
      const int K0 = (wv * 2 + u) * 8;
      const int key = K0 + drow;
      const int gs = (dslot + key) & 7;
      gl2lds(&kb[(size_t)(c * 64 + key) * HD + gs * 8], &Ks[buf][K0][0]);
    }
#pragma unroll
    for (int u = 0; u < 2; ++u) {
      const int D0 = (wv * 2 + u) * 8;
      const int d = D0 + drow;
      const int gs = (dslot + d) & 7;
      gl2lds(&vb[(size_t)d * TS + c * 64 + gs * 8], &Vs[buf][D0][0]);
    }
  };

  s8v qf[2];
#pragma unroll
  for (int kc = 0; kc < 2; ++kc)
    qf[kc] = *(const s8v*)&q[(size_t)(m0 + wv * 16 + n) * HD + kc * 32 + quad * 8];

  f4 o[4] = {fz, fz, fz, fz};
  f4 lD = fz;
  h8 ones;
#pragma unroll
  for (int j = 0; j < 8; ++j) ones[j] = (_Float16)1.0f;

  dmaKV(0, 0); dmaKV(1, 1);
  wait_barrier<4>();

  for (int t = 0; t < 32; ++t) {
    const int buf = t % 3;
    if (t < 30) dmaKV(t + 2, (t + 2) % 3);

    // K frags (swizzled slots): kf[f][kc] = K[key=f*16+n][kc*32+quad*8 ..]
    s8v kf[4][2];
#pragma unroll
    for (int f = 0; f < 4; ++f)
#pragma unroll
      for (int kc = 0; kc < 2; ++kc) {
        const int key = f * 16 + n;
        kf[f][kc] = *(const s8v*)&Ks[buf][key][(((kc * 4 + quad) - key) & 7) * 8];
      }

    // S^T = K Q^T: row=key(quad*4+i of tile f), col=q(n)
    f4 st[4];
#pragma unroll
    for (int f = 0; f < 4; ++f) {
      st[f] = __builtin_amdgcn_mfma_f32_16x16x32_bf16(kf[f][0], qf[0], fz, 0, 0, 0);
      st[f] = __builtin_amdgcn_mfma_f32_16x16x32_bf16(kf[f][1], qf[1], st[f], 0, 0, 0);
    }

    // P = exp2(S) in-register -> f16 A-frags
    h8 pa[2];
#pragma unroll
    for (int pr = 0; pr < 2; ++pr)
#pragma unroll
      for (int hf = 0; hf < 2; ++hf)
#pragma unroll
        for (int i = 0; i < 4; ++i)
          pa[pr][hf * 4 + i] = (_Float16)__builtin_amdgcn_exp2f(st[pr * 2 + hf][i]);

    // O += P V ; l += P * 1
#pragma unroll
    for (int pr = 0; pr < 2; ++pr) {
      lD = __builtin_amdgcn_mfma_f32_16x16x32_f16(pa[pr], ones, lD, 0, 0, 0);
#pragma unroll
      for (int g = 0; g < 4; ++g) {
        const int d = g * 16 + n;
        const h8 vf = *(const h8*)&Vs[buf][d][(((pr * 4 + quad) - d) & 7) * 8];
        o[g] = __builtin_amdgcn_mfma_f32_16x16x32_f16(pa[pr], vf, o[g], 0, 0, 0);
      }
    }

    if (t < 30)      wait_barrier<4>();
    else if (t < 31) wait_barrier<0>();
  }

  // epilogue: wave owns q rows m0+wv*16+quad*4+i; normalize by lD and store
#pragma unroll
  for (int i = 0; i < 4; ++i) {
    const float inv = 1.0f / lD[i];
    const size_t row = (size_t)(m0 + wv * 16 + quad * 4 + i) * HD;
#pragma unroll
    for (int g = 0; g < 4; ++g)
      out[row + g * 16 + n] = o[g][i] * inv;
  }
}

extern "C" void kernel_launch(void* const* d_in, const int* in_sizes, int n_in,
                              void* d_out, int out_size, void* d_ws, size_t ws_size,
                              hipStream_t stream) {
  const float* x  = (const float*)d_in[0];
  const float* Wk = (const float*)d_in[1];
  const float* Wq = (const float*)d_in[2];
  const float* Wv = (const float*)d_in[3];
  float* out = (float*)d_out;

  short* qb = (short*)d_ws;                           // [MTOT][64] bf16 (pre-scaled)
  short* kb = qb + (size_t)MTOT * HD;                 // [MTOT][64] bf16
  _Float16* vb = (_Float16*)(kb + (size_t)MTOT * HD); // [NB][64][TS] f16, key-swizzled
  short* wb = (short*)(vb + (size_t)NB * HD * TS);    // [192][1024] bf16 weights

  wconv_kernel<<<192, 256, 0, stream>>>(Wk, Wq, Wv, wb);
  proj_kernel<<<MTOT / 64, 256, 0, stream>>>(x, wb, qb, kb, vb);
  attn_kernel<<<MTOT / 64, 256, 0, stream>>>(qb, kb, vb, out);
}

// Round 7
// 129.512 us; speedup vs baseline: 1.3790x; 1.2389x over previous
//
#include <hip/hip_runtime.h>
#include <cstdint>

#define NB 8
#define TS 2048
#define NE 1024
#define HD 64
#define MTOT (NB*TS)

typedef float     f4  __attribute__((ext_vector_type(4)));
typedef short     s8v __attribute__((ext_vector_type(8)));
typedef short     s4v __attribute__((ext_vector_type(4)));
typedef int       i4v __attribute__((ext_vector_type(4)));
typedef _Float16  h8  __attribute__((ext_vector_type(8)));

__device__ __forceinline__ short f2bf(float f) {  // RNE
  union { float f; uint32_t u; } x; x.f = f;
  return (short)((x.u + 0x7FFFu + ((x.u >> 16) & 1u)) >> 16);
}

// pack two fp32 -> (bf16(lo) | bf16(hi)<<16) via +0x8000 round + v_perm byte select
__device__ __forceinline__ int pack2(float lo, float hi) {
  union { float f; uint32_t u; } a, b; a.f = lo; b.f = hi;
  return (int)__builtin_amdgcn_perm(b.u + 0x8000u, a.u + 0x8000u, 0x07060302u);
}

// async global->LDS DMA, 16B/lane; lptr wave-uniform, lane i -> lptr + i*16
__device__ __forceinline__ void gl2lds(const void* gptr, void* lptr) {
  auto g = (const __attribute__((address_space(1))) uint32_t*)gptr;
  auto l = (__attribute__((address_space(3))) uint32_t*)lptr;
  __builtin_amdgcn_global_load_lds(g, l, 16, 0, 0);
}

// barrier that keeps N newest vmem ops in flight (AITER-style, never drain unless N=0)
template <int N>
__device__ __forceinline__ void wait_barrier() {
  asm volatile("s_waitcnt vmcnt(%0) lgkmcnt(0)" :: "n"(N) : "memory");
  __builtin_amdgcn_s_barrier();
}

// ---- kernel 0: W fp32 -> bf16 (q-scale folded). wb [192][1024]: 0-63 q, 64-127 k, 128-191 v
__global__ __launch_bounds__(256) void wconv_kernel(
    const float* __restrict__ Wk, const float* __restrict__ Wq, const float* __restrict__ Wv,
    short* __restrict__ wb)
{
  const int idx = (blockIdx.x * 256 + threadIdx.x) * 4;
  const int p = idx >> 16;
  const int off = idx & 65535;
  const float* W = (p == 0) ? Wq : (p == 1) ? Wk : Wv;
  const float s = (p == 0) ? 0.18033688011112042f : 1.0f; // (1/8)*log2(e)
  const float4 v = *(const float4*)&W[off];
  s4v h; h[0] = f2bf(v.x*s); h[1] = f2bf(v.y*s); h[2] = f2bf(v.z*s); h[3] = f2bf(v.w*s);
  *(s4v*)&wb[idx] = h;
}

// ---- kernel 1: fused qkv projection. grid 512 x 256 thr, tile 32 rows x 192 cols,
// wave = 16 rows x 96 cols. LDS exactly 80 KB -> 2 blocks/CU (8 waves/CU).
// x: 4-buf fp32 DMA (3-ahead issue); W: 2-buf bf16 DMA (1-ahead). XOR slot-swizzle.
__global__ __launch_bounds__(256) void proj_kernel(
    const float* __restrict__ x, const short* __restrict__ wb,
    short* __restrict__ qo, short* __restrict__ ko, _Float16* __restrict__ vo)
{
  __shared__ float Xs[4][32][64];    // 32 KB
  __shared__ short Ws[2][192][64];   // 48 KB
  const int tid = threadIdx.x;
  const int wv = tid >> 6, lane = tid & 63, n = lane & 15, quad = lane >> 4;
  const int mg = wv & 1, cg = wv >> 1;
  const int r0 = blockIdx.x * 32;
  const int xrow = lane >> 4, xslot = lane & 15;   // x DMA: 4 rows x 16 slots (16B fp32)
  const int wrow = lane >> 3, wslot = lane & 7;    // W DMA: 8 cols x 8 slots (16B bf16)

  auto dmaX = [&](int c, int buf) {
#pragma unroll
    for (int u = 0; u < 2; ++u) {
      const int R0 = (wv * 2 + u) * 4;
      const int row = R0 + xrow;
      const int gs = (xslot + row) & 15;
      gl2lds(&x[(size_t)(r0 + row) * NE + c * 64 + gs * 4], &Xs[buf][R0][0]);
    }
  };
  auto dmaW = [&](int c, int buf) {
#pragma unroll
    for (int u = 0; u < 6; ++u) {
      const int C0 = (wv * 6 + u) * 8;
      const int col = C0 + wrow;
      const int gs = (wslot + col) & 7;
      gl2lds(&wb[(size_t)col * NE + c * 64 + gs * 8], &Ws[buf][C0][0]);
    }
  };

  const f4 fz = {0.f, 0.f, 0.f, 0.f};
  f4 acc[6] = {fz, fz, fz, fz, fz, fz};

  auto compute = [&](int bw, int bx) {
    s8v a[2];
    const int row = mg * 16 + n;
#pragma unroll
    for (int kc = 0; kc < 2; ++kc) {
      const int u0 = kc * 8 + quad * 2;
      const float* pr = &Xs[bx][row][0];
      const f4 f0 = *(const f4*)(pr + (((u0    ) - row) & 15) * 4);
      const f4 f1 = *(const f4*)(pr + (((u0 + 1) - row) & 15) * 4);
      i4v ai;
      ai[0] = pack2(f0[0], f0[1]); ai[1] = pack2(f0[2], f0[3]);
      ai[2] = pack2(f1[0], f1[1]); ai[3] = pack2(f1[2], f1[3]);
      a[kc] = __builtin_bit_cast(s8v, ai);
    }
#pragma unroll
    for (int nf = 0; nf < 6; ++nf) {
      const int col = cg * 96 + nf * 16 + n;
      const s8v b0 = *(const s8v*)&Ws[bw][col][(((0 + quad) - col) & 7) * 8];
      const s8v b1 = *(const s8v*)&Ws[bw][col][(((4 + quad) - col) & 7) * 8];
      acc[nf] = __builtin_amdgcn_mfma_f32_16x16x32_bf16(a[0], b0, acc[nf], 0, 0, 0);
      acc[nf] = __builtin_amdgcn_mfma_f32_16x16x32_bf16(a[1], b1, acc[nf], 0, 0, 0);
    }
  };

  // prologue: W0 first, then X0..X2 (FIFO: waiting for X0 keeps X1,X2 in flight)
  dmaW(0, 0); dmaX(0, 0); dmaX(1, 1); dmaX(2, 2);
  wait_barrier<4>();

  for (int t = 0; t < 16; ++t) {
    if (t <= 14) dmaW(t + 1, (t + 1) & 1);   // W first (older in FIFO than this iter's X)
    if (t <= 12) dmaX(t + 3, (t + 3) & 3);
    compute(t & 1, t & 3);
    if (t <= 12)      wait_barrier<2>();     // keep X(t+3) flying; X(t+1),W(t+1) landed
    else if (t <= 14) wait_barrier<0>();     // tail
  }

  // epilogue: C row = quad*4+i, col = n (+16*nf)
#pragma unroll
  for (int nf = 0; nf < 6; ++nf) {
    const int gc = cg * 96 + nf * 16;
    const int p = gc >> 6;
    const int rcol = (gc & 63) + n;
#pragma unroll
    for (int i = 0; i < 4; ++i) {
      const int R = r0 + mg * 16 + quad * 4 + i;
      const float av = acc[nf][i];
      if (p == 0)      qo[(size_t)R * HD + rcol] = f2bf(av);
      else if (p == 1) ko[(size_t)R * HD + rcol] = f2bf(av);
      else {
        // V transposed [b][d][t'] + key-order swizzle so attn PV B-frags are single 16B loads
        const int t2 = R & (TS - 1), b = t2 & 31;
        const int pos = (t2 & ~31) | (((b >> 2) & 3) << 3) | (((b >> 4) & 1) << 2) | (b & 3);
        vo[(size_t)(R >> 11) * HD * TS + (size_t)rcol * TS + pos] = (_Float16)av;
      }
    }
  }
}

// ---- kernel 2: attention. grid 256 x 512 thr (8 waves). 64 q/block; waves 0-3 keys
// [0,1024), waves 4-7 keys [1024,2048). Per half: 64-key chunks, 3-buf 2-ahead DMA.
// S^T = K Q^T -> exp2 in-reg -> f16 PV; l via P*ones. 2-way combine in LDS overlay.
__global__ __launch_bounds__(512) void attn_kernel(
    const short* __restrict__ q, const short* __restrict__ k,
    const _Float16* __restrict__ vT, float* __restrict__ out)
{
  __shared__ __align__(16) char smem[98304];   // K[2][3][64][64]s | V[2][3][64][64]h
  const int tid = threadIdx.x;
  const int wv = tid >> 6, lane = tid & 63, n = lane & 15, quad = lane >> 4;
  const int half = wv >> 2, qw = wv & 3;
  const int batch = blockIdx.x & 7;            // XCD swizzle: batch K/V pinned per XCD L2
  const int qg = blockIdx.x >> 3;
  const int m0 = batch * TS + qg * 64;
  const short*    kb = k  + (size_t)batch * TS * HD;
  const _Float16* vb = vT + (size_t)batch * HD * TS;
  const int drow = lane >> 3, dslot = lane & 7;
  const f4 fz = {0.f, 0.f, 0.f, 0.f};

  auto kbuf = [&](int buf) { return (short*)   (smem +         (half * 3 + buf) * 8192); };
  auto vbuf = [&](int buf) { return (_Float16*)(smem + 49152 + (half * 3 + buf) * 8192); };

  auto dmaKV = [&](int tt, int buf) {
    const int c = half * 16 + tt;
#pragma unroll
    for (int u = 0; u < 2; ++u) {
      const int K0 = (qw * 2 + u) * 8;
      const int key = K0 + drow;
      const int gs = (dslot + key) & 7;
      gl2lds(&kb[(size_t)(c * 64 + key) * HD + gs * 8], kbuf(buf) + K0 * 64);
    }
#pragma unroll
    for (int u = 0; u < 2; ++u) {
      const int D0 = (qw * 2 + u) * 8;
      const int d = D0 + drow;
      const int gs = (dslot + d) & 7;
      gl2lds(&vb[(size_t)d * TS + c * 64 + gs * 8], vbuf(buf) + D0 * 64);
    }
  };

  s8v qf[2];
#pragma unroll
  for (int kc = 0; kc < 2; ++kc)
    qf[kc] = *(const s8v*)&q[(size_t)(m0 + qw * 16 + n) * HD + kc * 32 + quad * 8];

  f4 o[4] = {fz, fz, fz, fz};
  f4 lD = fz;
  h8 ones;
#pragma unroll
  for (int j = 0; j < 8; ++j) ones[j] = (_Float16)1.0f;

  dmaKV(0, 0); dmaKV(1, 1);
  wait_barrier<4>();

  for (int t = 0; t < 16; ++t) {
    const int buf = t % 3;
    if (t <= 13) dmaKV(t + 2, (t + 2) % 3);

    const short*    ks = kbuf(buf);
    const _Float16* vs = vbuf(buf);

    s8v kf[4][2];
#pragma unroll
    for (int f = 0; f < 4; ++f)
#pragma unroll
      for (int kc = 0; kc < 2; ++kc) {
        const int key = f * 16 + n;
        kf[f][kc] = *(const s8v*)&ks[key * 64 + (((kc * 4 + quad) - key) & 7) * 8];
      }

    f4 st[4];
#pragma unroll
    for (int f = 0; f < 4; ++f) {
      st[f] = __builtin_amdgcn_mfma_f32_16x16x32_bf16(kf[f][0], qf[0], fz, 0, 0, 0);
      st[f] = __builtin_amdgcn_mfma_f32_16x16x32_bf16(kf[f][1], qf[1], st[f], 0, 0, 0);
    }

    h8 pa[2];
#pragma unroll
    for (int pr = 0; pr < 2; ++pr)
#pragma unroll
      for (int hf = 0; hf < 2; ++hf)
#pragma unroll
        for (int i = 0; i < 4; ++i)
          pa[pr][hf * 4 + i] = (_Float16)__builtin_amdgcn_exp2f(st[pr * 2 + hf][i]);

#pragma unroll
    for (int pr = 0; pr < 2; ++pr) {
      lD = __builtin_amdgcn_mfma_f32_16x16x32_f16(pa[pr], ones, lD, 0, 0, 0);
#pragma unroll
      for (int g = 0; g < 4; ++g) {
        const int d = g * 16 + n;
        const h8 vf = *(const h8*)&vs[d * 64 + (((pr * 4 + quad) - d) & 7) * 8];
        o[g] = __builtin_amdgcn_mfma_f32_16x16x32_f16(pa[pr], vf, o[g], 0, 0, 0);
      }
    }

    if (t <= 13)      wait_barrier<4>();   // chunk t+1 landed; t+2 stays in flight
    else if (t == 14) wait_barrier<0>();
  }

  __syncthreads();   // all waves done with K/V LDS before overlay

  float* o_c = (float*)smem;                 // [8][16][68]
  float* l_c = (float*)(smem + 36864);       // [8][16]
  if (n == 0)
#pragma unroll
    for (int i = 0; i < 4; ++i) l_c[wv * 16 + quad * 4 + i] = lD[i];
#pragma unroll
  for (int g = 0; g < 4; ++g)
#pragma unroll
    for (int i = 0; i < 4; ++i)
      o_c[(wv * 16 + quad * 4 + i) * 68 + g * 16 + n] = o[g][i];
  __syncthreads();

  // combine halves: 1024 outputs-groups (64 q x 16 d4), 512 thr x 2 reps
#pragma unroll
  for (int rep = 0; rep < 2; ++rep) {
    const int idx = tid + rep * 512;
    const int qr = idx >> 4, d4 = (idx & 15) * 4;
    const int qw2 = qr >> 4, wr = qr & 15;
    const float L = l_c[qw2 * 16 + wr] + l_c[(qw2 + 4) * 16 + wr];
    const f4 s0 = *(const f4*)&o_c[(qw2 * 16 + wr) * 68 + d4];
    const f4 s1 = *(const f4*)&o_c[((qw2 + 4) * 16 + wr) * 68 + d4];
    f4 r = (s0 + s1);
    const float inv = 1.0f / L;
    r[0] *= inv; r[1] *= inv; r[2] *= inv; r[3] *= inv;
    *(f4*)&out[(size_t)(m0 + qr) * HD + d4] = r;
  }
}

extern "C" void kernel_launch(void* const* d_in, const int* in_sizes, int n_in,
                              void* d_out, int out_size, void* d_ws, size_t ws_size,
                              hipStream_t stream) {
  const float* x  = (const float*)d_in[0];
  const float* Wk = (const float*)d_in[1];
  const float* Wq = (const float*)d_in[2];
  const float* Wv = (const float*)d_in[3];
  float* out = (float*)d_out;

  short* qb = (short*)d_ws;                           // [MTOT][64] bf16 (pre-scaled)
  short* kb = qb + (size_t)MTOT * HD;                 // [MTOT][64] bf16
  _Float16* vb = (_Float16*)(kb + (size_t)MTOT * HD); // [NB][64][TS] f16, key-swizzled
  short* wb = (short*)(vb + (size_t)NB * HD * TS);    // [192][1024] bf16 weights

  wconv_kernel<<<192, 256, 0, stream>>>(Wk, Wq, Wv, wb);
  proj_kernel<<<MTOT / 32, 256, 0, stream>>>(x, wb, qb, kb, vb);
  attn_kernel<<<MTOT / 64, 512, 0, stream>>>(qb, kb, vb, out);
}